// Round 7
// baseline (144.790 us; speedup 1.0000x reference)
//
#include <hip/hip_runtime.h>
#include <hip/hip_fp16.h>

#define OC 128
#define V_SZ 30000
#define KW 5
#define L_IN 2560              // 40*64
#define L_OUT (L_IN - KW + 1)  // 2556
#define NB 32
#define TCO 4
#define K_ROW (V_SZ * KW)      // 150000 floats per oc row
#define NI (V_SZ * KW)         // i = v*5+w index space
#define NT 40                  // 64-l conv tiles

// ---------------------------------------------------------------------------
// Kernel A: transpose + fp16-convert  K[oc][i] (f32) -> Kth[i][oc] (f16).
// Tile: 48 i x 128 oc (3125 blocks exactly). Block 256.  (unchanged from R6)
// ---------------------------------------------------------------------------
__global__ __launch_bounds__(256) void transpose_k(const float* __restrict__ K,
                                                   __half* __restrict__ Kth) {
    __shared__ float lds[48 * 132];
    const int i0  = blockIdx.x * 48;
    const int tid = threadIdx.x;

    {
        const int ii4 = (tid & 3) * 4;
        const int ocr = tid >> 2;   // 0..63
        #pragma unroll
        for (int p = 0; p < 3; ++p) {
            #pragma unroll
            for (int r = 0; r < 2; ++r) {
                const int oc = r * 64 + ocr;
                const int ii = p * 16 + ii4;
                const float4 kv = *reinterpret_cast<const float4*>(
                    &K[(size_t)oc * K_ROW + i0 + ii]);
                lds[(ii + 0) * 132 + oc] = kv.x;
                lds[(ii + 1) * 132 + oc] = kv.y;
                lds[(ii + 2) * 132 + oc] = kv.z;
                lds[(ii + 3) * 132 + oc] = kv.w;
            }
        }
    }
    __syncthreads();
    {
        const int oc8 = (tid & 15) * 8;
        #pragma unroll
        for (int p = 0; p < 3; ++p) {
            const int i_loc = p * 16 + (tid >> 4);
            __half h[8];
            #pragma unroll
            for (int k = 0; k < 8; ++k) h[k] = __float2half(lds[i_loc * 132 + oc8 + k]);
            *reinterpret_cast<float4*>(&Kth[(size_t)(i0 + i_loc) * OC + oc8]) =
                *reinterpret_cast<const float4*>(h);
        }
    }
}

// ---------------------------------------------------------------------------
// Kernel B: conv + relu + max-pool from fp16 Kth.
// Grid: (NT=40 l-tiles of 64, 32 b) = 1280 blocks. Block 256 = 16 lgrps x
// 16 oc8-lanes. Each thread: 4 l's x 5 half8 gathers (20 loads in flight).
// Per-block partial max written to ws (no atomics, no memset needed).
// ---------------------------------------------------------------------------
__global__ __launch_bounds__(256) void conv_max(const int* __restrict__ tokens,
                                                const __half* __restrict__ Kth,
                                                float* __restrict__ partial) {
    __shared__ int   ids[64 + KW - 1];   // 68
    __shared__ float red[16 * 128];
    const int b   = blockIdx.y;
    const int l0  = blockIdx.x * 64;
    const int tid = threadIdx.x;

    if (tid < 68) {
        const int l = l0 + tid;
        ids[tid] = (l < L_IN) ? tokens[b * L_IN + l] : 0;
    }
    __syncthreads();

    const int lgrp = tid >> 4;        // 0..15
    const int oc8  = (tid & 15) * 8;  // 0..120

    float acc[8];
    #pragma unroll
    for (int k = 0; k < 8; ++k) acc[k] = 0.f;

    #pragma unroll
    for (int u = 0; u < 4; ++u) {
        const int li = u * 16 + lgrp;     // 0..63
        const int l  = l0 + li;
        if (l < L_OUT) {
            float s[8];
            #pragma unroll
            for (int k = 0; k < 8; ++k) s[k] = 0.f;
            #pragma unroll
            for (int w = 0; w < KW; ++w) {
                const int id = ids[li + w];
                const float4 raw = *reinterpret_cast<const float4*>(
                    &Kth[((size_t)id * KW + w) * OC + oc8]);
                const __half* h = reinterpret_cast<const __half*>(&raw);
                #pragma unroll
                for (int k = 0; k < 8; ++k) s[k] += __half2float(h[k]);
            }
            #pragma unroll
            for (int k = 0; k < 8; ++k) acc[k] = fmaxf(acc[k], s[k]);
        }
    }

    #pragma unroll
    for (int k = 0; k < 8; ++k) red[lgrp * 128 + oc8 + k] = acc[k];
    __syncthreads();

    if (tid < 128) {
        float m = red[tid];
        #pragma unroll
        for (int g = 1; g < 16; ++g) m = fmaxf(m, red[g * 128 + tid]);
        // every slot written unconditionally -> no init required
        partial[((size_t)b * NT + blockIdx.x) * OC + tid] = m;
    }
}

// ---------------------------------------------------------------------------
// Kernel C: reduce partials -> pooled, then FC head.
// Grid 32 (one block per b), 128 threads (one per oc).
// ---------------------------------------------------------------------------
__global__ __launch_bounds__(128) void head(const float* __restrict__ partial,
                                            const float* __restrict__ fc1w,
                                            const float* __restrict__ fc1b,
                                            float* __restrict__ out) {
    __shared__ float pooled[OC];
    const int b  = blockIdx.x;
    const int oc = threadIdx.x;

    float m = 0.f;
    #pragma unroll 8
    for (int t = 0; t < NT; ++t)
        m = fmaxf(m, partial[((size_t)b * NT + t) * OC + oc]);  // coalesced
    pooled[oc] = m;
    __syncthreads();

    if (oc < TCO) {
        float acc = fc1b[oc];
        #pragma unroll 4
        for (int c = 0; c < OC; ++c)
            acc += pooled[c] * fc1w[oc * OC + c];
        out[b * TCO + oc] = acc;
    }
}

// ---------------------------------------------------------------------------
// Fallback (ws too small): gather from original f32 layout, atomics path.
// ---------------------------------------------------------------------------
__global__ __launch_bounds__(256) void conv_max_fallback(const int* __restrict__ tokens,
                                                         const float* __restrict__ K,
                                                         int* __restrict__ pooled) {
    const int b   = blockIdx.y;
    const int l0  = blockIdx.x * 64;
    const int tid = threadIdx.x;

    __shared__ int ids[64 + KW - 1];
    if (tid < 64 + KW - 1) {
        const int l = l0 + tid;
        ids[tid] = (l < L_IN) ? tokens[b * L_IN + l] : 0;
    }
    __syncthreads();

    const int oc   = tid & 127;
    const int half = tid >> 7;
    float m = 0.f;
    for (int u = 0; u < 32; ++u) {
        const int li = u * 2 + half;
        const int l  = l0 + li;
        if (l < L_OUT) {
            float s = 0.f;
            #pragma unroll
            for (int w = 0; w < KW; ++w)
                s += K[(size_t)oc * K_ROW + ids[li + w] * KW + w];
            m = fmaxf(m, s);
        }
    }
    atomicMax(&pooled[b * OC + oc], __float_as_int(m));
}

__global__ __launch_bounds__(128) void head_fallback(const int* __restrict__ pooled,
                                                     const float* __restrict__ fc1w,
                                                     const float* __restrict__ fc1b,
                                                     float* __restrict__ out) {
    const int tid = threadIdx.x;
    const int b = tid >> 2;
    const int t = tid & 3;
    float acc = fc1b[t];
    #pragma unroll 4
    for (int oc = 0; oc < OC; ++oc)
        acc += __int_as_float(pooled[b * OC + oc]) * fc1w[t * OC + oc];
    out[b * TCO + t] = acc;
}

extern "C" void kernel_launch(void* const* d_in, const int* in_sizes, int n_in,
                              void* d_out, int out_size, void* d_ws, size_t ws_size,
                              hipStream_t stream) {
    const int*   tokens = (const int*)d_in[0];
    const float* K      = (const float*)d_in[1];
    const float* fc1w   = (const float*)d_in[2];
    const float* fc1b   = (const float*)d_in[3];
    float*       out    = (float*)d_out;

    const size_t kthBytes     = (size_t)NI * OC * sizeof(__half);       // 38.4 MB
    const size_t partialBytes = (size_t)NB * NT * OC * sizeof(float);   // 655 KB

    if (ws_size >= kthBytes + partialBytes) {
        __half* Kth    = (__half*)d_ws;
        float* partial = (float*)((char*)d_ws + kthBytes);
        transpose_k<<<NI / 48, 256, 0, stream>>>(K, Kth);               // 3125 blocks
        conv_max<<<dim3(NT, NB), 256, 0, stream>>>(tokens, Kth, partial); // 1280 blocks
        head<<<NB, 128, 0, stream>>>(partial, fc1w, fc1b, out);
    } else {
        int* pooled = (int*)d_ws;
        hipMemsetAsync(pooled, 0, (size_t)NB * OC * sizeof(int), stream);
        conv_max_fallback<<<dim3((L_OUT + 63) / 64, NB), 256, 0, stream>>>(tokens, K, pooled);
        head_fallback<<<1, 128, 0, stream>>>(pooled, fc1w, fc1b, out);
    }
}